// Round 7
// baseline (118306.018 us; speedup 1.0000x reference)
//
#include <hip/hip_runtime.h>
#include <stdint.h>

#define T_STEPS 32768
#define HDIM    1024
#define LDIM    512
#define ADIM    32
#define NWG     128   // workgroups in recurrence kernel
#define NOUT    8     // belief outputs per WG (NWG*NOUT == HDIM)

__device__ __forceinline__ float fast_sigmoid(float x) {
    float e = __expf(-x);
    return __builtin_amdgcn_rcpf(1.0f + e);
}
__device__ __forceinline__ float fast_tanh(float x) {
    // tanh(x) = 1 - 2/(1+e^(2x)); exact at +-inf, ~2ulp elsewhere
    float e = __expf(2.0f * x);
    return 1.0f - 2.0f * __builtin_amdgcn_rcpf(1.0f + e);
}

// ---------------------------------------------------------------------------
// Encoder: z[t,m] = tanh( sum_k obs[t,k]*enc_w[m,k] + enc_b[m] )
// ---------------------------------------------------------------------------
__global__ __launch_bounds__(256) void encoder_kernel(
    const float* __restrict__ obs,    // (T,128)
    const float* __restrict__ w,      // (512,128)
    const float* __restrict__ b,      // (512)
    float* __restrict__ z)            // (T,512)
{
    __shared__ float As[64][65];
    __shared__ float Bs[64][65];

    const int tile_n = blockIdx.x;  // 0..7   (m tiles)
    const int tile_t = blockIdx.y;  // 0..511 (t tiles)
    const int tid = threadIdx.x;
    const int ty = tid >> 4;
    const int tx = tid & 15;

    float acc[4][4] = {};

    for (int kt = 0; kt < 2; ++kt) {
        #pragma unroll
        for (int it = 0; it < 4; ++it) {
            int lin = it * 1024 + tid * 4;
            int r = lin >> 6, c = lin & 63;
            float4 va = *(const float4*)&obs[(size_t)(tile_t * 64 + r) * 128 + kt * 64 + c];
            As[r][c] = va.x; As[r][c+1] = va.y; As[r][c+2] = va.z; As[r][c+3] = va.w;
            float4 vb = *(const float4*)&w[(size_t)(tile_n * 64 + r) * 128 + kt * 64 + c];
            Bs[r][c] = vb.x; Bs[r][c+1] = vb.y; Bs[r][c+2] = vb.z; Bs[r][c+3] = vb.w;
        }
        __syncthreads();

        for (int k = 0; k < 64; ++k) {
            float av[4], bv[4];
            #pragma unroll
            for (int a = 0; a < 4; ++a) av[a] = As[ty * 4 + a][k];
            #pragma unroll
            for (int c = 0; c < 4; ++c) bv[c] = Bs[tx * 4 + c][k];
            #pragma unroll
            for (int a = 0; a < 4; ++a)
                #pragma unroll
                for (int c = 0; c < 4; ++c)
                    acc[a][c] = fmaf(av[a], bv[c], acc[a][c]);
        }
        __syncthreads();
    }

    #pragma unroll
    for (int a = 0; a < 4; ++a) {
        int row = tile_t * 64 + ty * 4 + a;
        #pragma unroll
        for (int c = 0; c < 4; ++c) {
            int col = tile_n * 64 + tx * 4 + c;
            z[(size_t)row * LDIM + col] = tanhf(acc[a][c] + b[col]);
        }
    }
}

// ---------------------------------------------------------------------------
// GRU recurrence. NWG x 256 threads, cooperative launch.
// Sync: tag-in-data ({tag=t+1 | float bits} uint64), parity double-buffered
// hbuf, agent scope (R4 scheme). Critical-path slimming this round:
//  - ONE barrier per step. h_lds is parity double-buffered: pollers at step
//    t+1 write buffer pb' != pb read by compute at step t; the single B1
//    separates same-buffer reuse two steps apart (barrier argument in notes).
//  - lane0 publishes DIRECTLY after the gate math (no h_pub LDS stage, no B2).
//  - 'hold' (own h) carried in a lane0 register, not re-read from LDS.
//  - gates use v_exp/v_rcp (fast_sigmoid/fast_tanh) instead of libm.
//  - z/act prefetch split: issue loads right after B1, LDS-write into the
//    nxt parity buffer after compute -> HBM/L2 latency off the step path.
// ---------------------------------------------------------------------------
__global__ __launch_bounds__(256, 1) void gru_kernel(
    float* __restrict__ out,          // (T, 1024) == beliefs
    const float* __restrict__ z_seq,  // (T, 512)
    const float* __restrict__ act,    // (T, 32)
    const float* __restrict__ w_ih,   // (3072, 544)
    const float* __restrict__ w_hh,   // (3072, 1024)
    const float* __restrict__ b_ih,   // (3072)
    const float* __restrict__ b_hh,   // (3072)
    uint64_t* __restrict__ hbuf)      // (2, 1024) packed, zeroed before launch
{
    __shared__ float h_lds[2][HDIM];
    __shared__ float z_lds[2][LDIM];
    __shared__ float a_lds[2][ADIM];

    const int tid  = threadIdx.x;
    const int wg   = blockIdx.x;
    const int grp  = tid >> 5;        // 0..7
    const int lane = tid & 31;
    const int i    = wg * NOUT + grp; // global output index 0..1023

    // ---- load weight slices into registers (once) and PIN them ----
    float whr[32], whz[32], whn[32];
    {
        const float* pr = &w_hh[(size_t)i * HDIM + lane];
        const float* pz = &w_hh[(size_t)(HDIM + i) * HDIM + lane];
        const float* pn = &w_hh[(size_t)(2 * HDIM + i) * HDIM + lane];
        #pragma unroll
        for (int j = 0; j < 32; ++j) {
            whr[j] = pr[32 * j]; whz[j] = pz[32 * j]; whn[j] = pn[32 * j];
        }
    }
    float wir[17], wiz[17], win[17];
    {
        const float* pr = &w_ih[(size_t)i * 544 + lane];
        const float* pz = &w_ih[(size_t)(HDIM + i) * 544 + lane];
        const float* pn = &w_ih[(size_t)(2 * HDIM + i) * 544 + lane];
        #pragma unroll
        for (int j = 0; j < 17; ++j) {
            wir[j] = pr[32 * j]; wiz[j] = pz[32 * j]; win[j] = pn[32 * j];
        }
    }
    #pragma unroll
    for (int j = 0; j < 32; ++j) {
        asm volatile("" : "+v"(whr[j]), "+v"(whz[j]), "+v"(whn[j]));
    }
    #pragma unroll
    for (int j = 0; j < 17; ++j) {
        asm volatile("" : "+v"(wir[j]), "+v"(wiz[j]), "+v"(win[j]));
    }

    // pre-merged biases for r/z (their ih+hh sums are combined pre-sigmoid)
    const float bias_r = b_ih[i] + b_hh[i];
    const float bias_z = b_ih[HDIM + i] + b_hh[HDIM + i];
    const float bin_   = b_ih[2 * HDIM + i];
    const float bhn    = b_hh[2 * HDIM + i];

    // ---- prologue: h(into pb-of-t0 buffer 1)=0, z row 0, act row 0 ----
    for (int q = tid; q < HDIM; q += 256) h_lds[1][q] = 0.0f;
    if (tid < 128) {
        float4 v = *(const float4*)&z_seq[tid * 4];
        *(float4*)&z_lds[0][tid * 4] = v;
        if (tid < 8) *(float4*)&a_lds[0][tid * 4] = make_float4(0.f, 0.f, 0.f, 0.f);
    }
    float hold = 0.0f;   // lane0 of each group carries its own h in a register
    __syncthreads();

    for (int t = 0; t < T_STEPS; ++t) {
        const int cur = t & 1;            // z/a buffer for this step
        const int pb  = (t + 1) & 1;      // == (t-1)&1: h buffer for this step

        if (tid >= 128 && t > 0) {
            // ---- poll one 64B line (8 tagged words) of h(t-1) ----
            const int q = tid - 128;                 // 0..127 -> line q
            const uint64_t* bp = hbuf + (size_t)pb * HDIM + q * 8;
            const uint32_t want = (uint32_t)t;
            uint64_t v[8];
            int done = 0;
            while (done != 0xFF) {
                #pragma unroll
                for (int k = 0; k < 8; ++k) {
                    if (!(done & (1 << k))) {
                        v[k] = __hip_atomic_load(bp + k, __ATOMIC_RELAXED,
                                                 __HIP_MEMORY_SCOPE_AGENT);
                    }
                }
                #pragma unroll
                for (int k = 0; k < 8; ++k) {
                    if (!(done & (1 << k)) && (uint32_t)(v[k] >> 32) == want)
                        done |= (1 << k);
                }
            }
            float4 h0, h1;
            h0.x = __uint_as_float((uint32_t)v[0]);
            h0.y = __uint_as_float((uint32_t)v[1]);
            h0.z = __uint_as_float((uint32_t)v[2]);
            h0.w = __uint_as_float((uint32_t)v[3]);
            h1.x = __uint_as_float((uint32_t)v[4]);
            h1.y = __uint_as_float((uint32_t)v[5]);
            h1.z = __uint_as_float((uint32_t)v[6]);
            h1.w = __uint_as_float((uint32_t)v[7]);
            *(float4*)&h_lds[pb][q * 8]     = h0;
            *(float4*)&h_lds[pb][q * 8 + 4] = h1;
        }
        __syncthreads();   // B1 (the only barrier per step)

        // ---- prefetch issue for step t+1 (in flight across compute) ----
        float4 zpre, apre;
        if (tid < 128) {
            int tn = (t + 1 < T_STEPS) ? (t + 1) : t;
            zpre = *(const float4*)&z_seq[(size_t)tn * LDIM + tid * 4];
            if (tid < 8) {
                // step t+1 consumes act[t]
                apre = *(const float4*)&act[(size_t)t * ADIM + tid * 4];
            }
        }

        // ---- matvec partials: hh-side (1024) and ih-side (544) ----
        float sr = 0.f, sz = 0.f, sn = 0.f;
        #pragma unroll
        for (int j = 0; j < 32; ++j) {
            float hv = h_lds[pb][lane + 32 * j];
            sr = fmaf(whr[j], hv, sr);
            sz = fmaf(whz[j], hv, sz);
            sn = fmaf(whn[j], hv, sn);
        }
        float gr = 0.f, gz = 0.f, gn = 0.f;
        #pragma unroll
        for (int j = 0; j < 16; ++j) {
            float xv = z_lds[cur][lane + 32 * j];
            gr = fmaf(wir[j], xv, gr);
            gz = fmaf(wiz[j], xv, gz);
            gn = fmaf(win[j], xv, gn);
        }
        {
            float xa = a_lds[cur][lane];
            gr = fmaf(wir[16], xa, gr);
            gz = fmaf(wiz[16], xa, gz);
            gn = fmaf(win[16], xa, gn);
        }

        float vr = sr + gr, vz = sz + gz;
        #pragma unroll
        for (int m = 16; m >= 1; m >>= 1) {
            vr += __shfl_xor(vr, m);
            vz += __shfl_xor(vz, m);
            sn += __shfl_xor(sn, m);
            gn += __shfl_xor(gn, m);
        }

        if (lane == 0) {
            float r    = fast_sigmoid(vr + bias_r);
            float zg   = fast_sigmoid(vz + bias_z);
            float n    = fast_tanh(gn + bin_ + r * (sn + bhn));
            float hnew = (1.0f - zg) * n + zg * hold;
            hold = hnew;
            // publish directly (critical path), then the plain out store
            uint64_t pk = ((uint64_t)(uint32_t)(t + 1) << 32) |
                          (uint64_t)__float_as_uint(hnew);
            __hip_atomic_store(&hbuf[(size_t)cur * HDIM + i], pk,
                               __ATOMIC_RELAXED, __HIP_MEMORY_SCOPE_AGENT);
            out[(size_t)t * HDIM + i] = hnew;
        }

        // ---- late LDS write of prefetched inputs into the nxt buffers ----
        if (tid < 128) {
            *(float4*)&z_lds[cur ^ 1][tid * 4] = zpre;
            if (tid < 8) *(float4*)&a_lds[cur ^ 1][tid * 4] = apre;
        }
        // next iteration's B1 orders these writes before their reads
    }
}

// ---------------------------------------------------------------------------
extern "C" void kernel_launch(void* const* d_in, const int* in_sizes, int n_in,
                              void* d_out, int out_size, void* d_ws, size_t ws_size,
                              hipStream_t stream) {
    const float* obs   = (const float*)d_in[0];
    const float* act   = (const float*)d_in[1];
    const float* enc_w = (const float*)d_in[2];
    const float* enc_b = (const float*)d_in[3];
    const float* w_ih  = (const float*)d_in[4];
    const float* w_hh  = (const float*)d_in[5];
    const float* b_ih  = (const float*)d_in[6];
    const float* b_hh  = (const float*)d_in[7];
    float* out = (float*)d_out;

    // ws layout: [0, 16KB) tagged h double-buffer ; [64KB, ...) z_seq
    uint64_t* hbuf  = (uint64_t*)d_ws;
    float*    z_seq = (float*)((char*)d_ws + 65536);

    hipMemsetAsync(hbuf, 0, 2 * HDIM * sizeof(uint64_t), stream);

    encoder_kernel<<<dim3(8, 512), 256, 0, stream>>>(obs, enc_w, enc_b, z_seq);

    void* args[] = {(void*)&out, (void*)&z_seq, (void*)&act, (void*)&w_ih,
                    (void*)&w_hh, (void*)&b_ih, (void*)&b_hh, (void*)&hbuf};
    hipLaunchCooperativeKernel((void*)gru_kernel, dim3(NWG), dim3(256),
                               args, 0, stream);
}

// Round 8
// 87007.928 us; speedup vs baseline: 1.3597x; 1.3597x over previous
//
#include <hip/hip_runtime.h>
#include <stdint.h>

#define T_STEPS 32768
#define HDIM    1024
#define LDIM    512
#define ADIM    32
#define NWG     128   // workgroups in recurrence kernel
#define NOUT    8     // belief outputs per WG (NWG*NOUT == HDIM)

__device__ __forceinline__ float fast_sigmoid(float x) {
    float e = __expf(-x);
    return __builtin_amdgcn_rcpf(1.0f + e);
}
__device__ __forceinline__ float fast_tanh(float x) {
    // tanh(x) = 1 - 2/(1+e^(2x)); exact at +-inf, ~2ulp elsewhere
    float e = __expf(2.0f * x);
    return 1.0f - 2.0f * __builtin_amdgcn_rcpf(1.0f + e);
}

// ---------------------------------------------------------------------------
// Encoder: z[t,m] = tanh( sum_k obs[t,k]*enc_w[m,k] + enc_b[m] )
// ---------------------------------------------------------------------------
__global__ __launch_bounds__(256) void encoder_kernel(
    const float* __restrict__ obs,    // (T,128)
    const float* __restrict__ w,      // (512,128)
    const float* __restrict__ b,      // (512)
    float* __restrict__ z)            // (T,512)
{
    __shared__ float As[64][65];
    __shared__ float Bs[64][65];

    const int tile_n = blockIdx.x;  // 0..7   (m tiles)
    const int tile_t = blockIdx.y;  // 0..511 (t tiles)
    const int tid = threadIdx.x;
    const int ty = tid >> 4;
    const int tx = tid & 15;

    float acc[4][4] = {};

    for (int kt = 0; kt < 2; ++kt) {
        #pragma unroll
        for (int it = 0; it < 4; ++it) {
            int lin = it * 1024 + tid * 4;
            int r = lin >> 6, c = lin & 63;
            float4 va = *(const float4*)&obs[(size_t)(tile_t * 64 + r) * 128 + kt * 64 + c];
            As[r][c] = va.x; As[r][c+1] = va.y; As[r][c+2] = va.z; As[r][c+3] = va.w;
            float4 vb = *(const float4*)&w[(size_t)(tile_n * 64 + r) * 128 + kt * 64 + c];
            Bs[r][c] = vb.x; Bs[r][c+1] = vb.y; Bs[r][c+2] = vb.z; Bs[r][c+3] = vb.w;
        }
        __syncthreads();

        for (int k = 0; k < 64; ++k) {
            float av[4], bv[4];
            #pragma unroll
            for (int a = 0; a < 4; ++a) av[a] = As[ty * 4 + a][k];
            #pragma unroll
            for (int c = 0; c < 4; ++c) bv[c] = Bs[tx * 4 + c][k];
            #pragma unroll
            for (int a = 0; a < 4; ++a)
                #pragma unroll
                for (int c = 0; c < 4; ++c)
                    acc[a][c] = fmaf(av[a], bv[c], acc[a][c]);
        }
        __syncthreads();
    }

    #pragma unroll
    for (int a = 0; a < 4; ++a) {
        int row = tile_t * 64 + ty * 4 + a;
        #pragma unroll
        for (int c = 0; c < 4; ++c) {
            int col = tile_n * 64 + tx * 4 + c;
            z[(size_t)row * LDIM + col] = tanhf(acc[a][c] + b[col]);
        }
    }
}

// ---------------------------------------------------------------------------
// GRU recurrence. NWG x 256 threads, cooperative launch.
// EXACT round-4 structure (best: 94.4ms): tag-in-data parity double-buffered
// hbuf, tid<128 stage z/act, tid>=128 poll one 64B line each, B1, compute,
// B2, single-wave coalesced publication of the WG's 8 tagged words.
// Round-8 micro-changes (lane0 serial-segment only, sync untouched):
//  - fast_sigmoid/fast_tanh (v_exp + v_rcp) instead of libm expf/tanhf
//  - 'hold' (group's own h) carried in a lane0 register, not re-read from LDS
//  - r/z biases pre-merged (b_ih+b_hh) outside the loop
// ---------------------------------------------------------------------------
__global__ __launch_bounds__(256, 1) void gru_kernel(
    float* __restrict__ out,          // (T, 1024) == beliefs
    const float* __restrict__ z_seq,  // (T, 512)
    const float* __restrict__ act,    // (T, 32)
    const float* __restrict__ w_ih,   // (3072, 544)
    const float* __restrict__ w_hh,   // (3072, 1024)
    const float* __restrict__ b_ih,   // (3072)
    const float* __restrict__ b_hh,   // (3072)
    uint64_t* __restrict__ hbuf)      // (2, 1024) packed, zeroed before launch
{
    __shared__ float h_lds[HDIM];
    __shared__ float z_lds[LDIM];
    __shared__ float a_lds[ADIM];
    __shared__ float h_pub[NOUT];

    const int tid  = threadIdx.x;
    const int wg   = blockIdx.x;
    const int grp  = tid >> 5;        // 0..7
    const int lane = tid & 31;
    const int i    = wg * NOUT + grp; // global output index 0..1023

    // ---- load weight slices into registers (once) and PIN them ----
    float whr[32], whz[32], whn[32];
    {
        const float* pr = &w_hh[(size_t)i * HDIM + lane];
        const float* pz = &w_hh[(size_t)(HDIM + i) * HDIM + lane];
        const float* pn = &w_hh[(size_t)(2 * HDIM + i) * HDIM + lane];
        #pragma unroll
        for (int j = 0; j < 32; ++j) {
            whr[j] = pr[32 * j]; whz[j] = pz[32 * j]; whn[j] = pn[32 * j];
        }
    }
    float wir[17], wiz[17], win[17];
    {
        const float* pr = &w_ih[(size_t)i * 544 + lane];
        const float* pz = &w_ih[(size_t)(HDIM + i) * 544 + lane];
        const float* pn = &w_ih[(size_t)(2 * HDIM + i) * 544 + lane];
        #pragma unroll
        for (int j = 0; j < 17; ++j) {
            wir[j] = pr[32 * j]; wiz[j] = pz[32 * j]; win[j] = pn[32 * j];
        }
    }
    #pragma unroll
    for (int j = 0; j < 32; ++j) {
        asm volatile("" : "+v"(whr[j]), "+v"(whz[j]), "+v"(whn[j]));
    }
    #pragma unroll
    for (int j = 0; j < 17; ++j) {
        asm volatile("" : "+v"(wir[j]), "+v"(wiz[j]), "+v"(win[j]));
    }

    // pre-merged biases for r/z (their ih+hh sums combine pre-sigmoid)
    const float bias_r = b_ih[i] + b_hh[i];
    const float bias_z = b_ih[HDIM + i] + b_hh[HDIM + i];
    const float bin_   = b_ih[2 * HDIM + i];
    const float bhn    = b_hh[2 * HDIM + i];

    for (int q = tid; q < HDIM; q += 256) h_lds[q] = 0.0f;
    float hold = 0.0f;   // lane0 of each group carries its own h in a register
    __syncthreads();

    for (int t = 0; t < T_STEPS; ++t) {
        if (tid < 128) {
            // ---- stage input-side data (overlaps other waves' h poll) ----
            float4 v = *(const float4*)&z_seq[(size_t)t * LDIM + tid * 4];
            *(float4*)&z_lds[tid * 4] = v;
            if (tid < ADIM) {
                a_lds[tid] = (t == 0) ? 0.0f : act[(size_t)(t - 1) * ADIM + tid];
            }
        } else if (t > 0) {
            // ---- poll one 64B line (8 tagged words) of h(t-1) ----
            const int q = tid - 128;                 // 0..127 -> line q
            const uint64_t* bp = hbuf + ((size_t)((t - 1) & 1)) * HDIM + q * 8;
            const uint32_t want = (uint32_t)t;
            uint64_t v[8];
            int done = 0;
            while (done != 0xFF) {
                #pragma unroll
                for (int k = 0; k < 8; ++k) {
                    if (!(done & (1 << k))) {
                        v[k] = __hip_atomic_load(bp + k, __ATOMIC_RELAXED,
                                                 __HIP_MEMORY_SCOPE_AGENT);
                    }
                }
                #pragma unroll
                for (int k = 0; k < 8; ++k) {
                    if (!(done & (1 << k)) && (uint32_t)(v[k] >> 32) == want)
                        done |= (1 << k);
                }
            }
            float4 h0, h1;
            h0.x = __uint_as_float((uint32_t)v[0]);
            h0.y = __uint_as_float((uint32_t)v[1]);
            h0.z = __uint_as_float((uint32_t)v[2]);
            h0.w = __uint_as_float((uint32_t)v[3]);
            h1.x = __uint_as_float((uint32_t)v[4]);
            h1.y = __uint_as_float((uint32_t)v[5]);
            h1.z = __uint_as_float((uint32_t)v[6]);
            h1.w = __uint_as_float((uint32_t)v[7]);
            *(float4*)&h_lds[q * 8]     = h0;
            *(float4*)&h_lds[q * 8 + 4] = h1;
        }
        __syncthreads();   // B1: h_lds/z_lds/a_lds ready

        // ---- matvec partials: hh-side (1024) and ih-side (544) ----
        float sr = 0.f, sz = 0.f, sn = 0.f;
        #pragma unroll
        for (int j = 0; j < 32; ++j) {
            float hv = h_lds[lane + 32 * j];
            sr = fmaf(whr[j], hv, sr);
            sz = fmaf(whz[j], hv, sz);
            sn = fmaf(whn[j], hv, sn);
        }
        float gr = 0.f, gz = 0.f, gn = 0.f;
        #pragma unroll
        for (int j = 0; j < 16; ++j) {
            float xv = z_lds[lane + 32 * j];
            gr = fmaf(wir[j], xv, gr);
            gz = fmaf(wiz[j], xv, gz);
            gn = fmaf(win[j], xv, gn);
        }
        {
            float xa = a_lds[lane];
            gr = fmaf(wir[16], xa, gr);
            gz = fmaf(wiz[16], xa, gz);
            gn = fmaf(win[16], xa, gn);
        }

        float vr = sr + gr, vz = sz + gz;
        #pragma unroll
        for (int m = 16; m >= 1; m >>= 1) {
            vr += __shfl_xor(vr, m);
            vz += __shfl_xor(vz, m);
            sn += __shfl_xor(sn, m);
            gn += __shfl_xor(gn, m);
        }

        if (lane == 0) {
            float r    = fast_sigmoid(vr + bias_r);
            float zg   = fast_sigmoid(vz + bias_z);
            float n    = fast_tanh(gn + bin_ + r * (sn + bhn));
            float hnew = (1.0f - zg) * n + zg * hold;
            hold = hnew;
            h_pub[grp] = hnew;
        }
        __syncthreads();   // B2: h_pub complete

        // ---- coalesced publication: one wave writes one 64B tagged line ----
        if (tid < NOUT) {
            uint64_t pk = ((uint64_t)(uint32_t)(t + 1) << 32) |
                          (uint64_t)__float_as_uint(h_pub[tid]);
            __hip_atomic_store(&hbuf[((size_t)(t & 1)) * HDIM + wg * NOUT + tid],
                               pk, __ATOMIC_RELAXED, __HIP_MEMORY_SCOPE_AGENT);
        } else if (tid == NOUT) {
            // out store off the critical path
            float4 o0 = *(const float4*)&h_pub[0];
            float4 o1 = *(const float4*)&h_pub[4];
            *(float4*)&out[(size_t)t * HDIM + wg * NOUT]     = o0;
            *(float4*)&out[(size_t)t * HDIM + wg * NOUT + 4] = o1;
        }
        // next iteration's B1 protects h_pub / h_lds / z_lds reuse
    }
}

// ---------------------------------------------------------------------------
extern "C" void kernel_launch(void* const* d_in, const int* in_sizes, int n_in,
                              void* d_out, int out_size, void* d_ws, size_t ws_size,
                              hipStream_t stream) {
    const float* obs   = (const float*)d_in[0];
    const float* act   = (const float*)d_in[1];
    const float* enc_w = (const float*)d_in[2];
    const float* enc_b = (const float*)d_in[3];
    const float* w_ih  = (const float*)d_in[4];
    const float* w_hh  = (const float*)d_in[5];
    const float* b_ih  = (const float*)d_in[6];
    const float* b_hh  = (const float*)d_in[7];
    float* out = (float*)d_out;

    // ws layout: [0, 16KB) tagged h double-buffer ; [64KB, ...) z_seq
    uint64_t* hbuf  = (uint64_t*)d_ws;
    float*    z_seq = (float*)((char*)d_ws + 65536);

    hipMemsetAsync(hbuf, 0, 2 * HDIM * sizeof(uint64_t), stream);

    encoder_kernel<<<dim3(8, 512), 256, 0, stream>>>(obs, enc_w, enc_b, z_seq);

    void* args[] = {(void*)&out, (void*)&z_seq, (void*)&act, (void*)&w_ih,
                    (void*)&w_hh, (void*)&b_ih, (void*)&b_hh, (void*)&hbuf};
    hipLaunchCooperativeKernel((void*)gru_kernel, dim3(NWG), dim3(256),
                               args, 0, stream);
}